// Round 1
// baseline (137.916 us; speedup 1.0000x reference)
//
#include <hip/hip_runtime.h>
#include <hip/hip_bf16.h>

// out = (Q K^T) V * scale, softmax discarded => associativity:
//   out_i = Q_i @ (K_i^T @ V_i) * scale over 32 blocks of 2048 flat rows of
//   the (65536,64) view of the (4096,1024) projections.
// R11: fuse the whole Q path. A 128-row tile of the Q projection maps exactly
// to one attention block (i = m0/128), so q_gemm_out computes the Q GEMM tile
// and multiplies by T_i (reduced from P in its prologue) in-LDS, writing `out`
// directly. Kernels: cvt, kv_gemm (z=2), kT, q_gemm_out. Removes reduce_T and
// qT launches, the TB buffer, and the 16.8 MB Q bf16 HBM round-trip.

#define E_DIM 1024
#define N_ROWS 4096

typedef __attribute__((ext_vector_type(8))) short bf16x8;
typedef __attribute__((ext_vector_type(4))) float f32x4;

// ---- ws layout (elements) ----
// QB [unused] KB [4194304) VB [8388608) bf16  (qkv base = ws)
// XB 12582912 WB 16777216 (bf16)
// P  float-offset 9961472 (32 blk x 8 chunks x 4096, [d][e])
#define KB_U 4194304
#define VB_U 8388608
#define XB_U 12582912
#define WB_U 16777216
#define P_F  9961472

__device__ __forceinline__ unsigned short f2b(float f) {
    union { float f; unsigned int i; } c; c.f = f;
    unsigned int r = c.i + 0x7FFFu + ((c.i >> 16) & 1u);   // RNE (finite data)
    return (unsigned short)(r >> 16);
}

__device__ __forceinline__ uint4 pack8(const f32x4 a, const f32x4 b) {
    uint4 o;
    o.x = (unsigned)f2b(a[0]) | ((unsigned)f2b(a[1]) << 16);
    o.y = (unsigned)f2b(a[2]) | ((unsigned)f2b(a[3]) << 16);
    o.z = (unsigned)f2b(b[0]) | ((unsigned)f2b(b[1]) << 16);
    o.w = (unsigned)f2b(b[2]) | ((unsigned)f2b(b[3]) << 16);
    return o;
}

typedef __attribute__((address_space(1))) const void* gptr_t;
typedef __attribute__((address_space(3))) void* lptr_t;
__device__ __forceinline__ void gl_lds16(const void* g, void* l) {
    __builtin_amdgcn_global_load_lds((gptr_t)g, (lptr_t)l, 16, 0, 0);
}

// swizzled index into a [row][64] LDS tile (8 slots of 8 elems per row)
__device__ __forceinline__ int sw_idx(int row, int r) {
    return row * 64 + (((((r) >> 3) & 7) ^ (row & 7)) << 3) + (r & 7);
}

// ---------------------------------------------------------------------------
// Kernel 0: fp32 -> bf16 convert: x (4 MB-segs) + Wq/Wk/Wv.
// ---------------------------------------------------------------------------
__global__ __launch_bounds__(256) void cvt_bf16(
    const float* __restrict__ x,  const float* __restrict__ wq,
    const float* __restrict__ wk, const float* __restrict__ wv,
    unsigned short* __restrict__ dst0)
{
    const int seg = blockIdx.y;
    const float* __restrict__ src;
    unsigned short* __restrict__ dst;
    if (seg < 4) { src = x + (size_t)seg * 1048576; dst = dst0 + (size_t)seg * 1048576; }
    else {
        src = (seg == 4) ? wq : (seg == 5) ? wk : wv;
        dst = dst0 + 4194304 + (size_t)(seg - 4) * 1048576;
    }
    const int i = blockIdx.x * 256 + threadIdx.x;   // 0..131071
    const float4 a = *(const float4*)(src + (size_t)i * 8);
    const float4 b = *(const float4*)(src + (size_t)i * 8 + 4);
    uint4 o;
    o.x = (unsigned)f2b(a.x) | ((unsigned)f2b(a.y) << 16);
    o.y = (unsigned)f2b(a.z) | ((unsigned)f2b(a.w) << 16);
    o.z = (unsigned)f2b(b.x) | ((unsigned)f2b(b.y) << 16);
    o.w = (unsigned)f2b(b.z) | ((unsigned)f2b(b.w) << 16);
    *(uint4*)(dst + (size_t)i * 8) = o;
}

// ---------------------------------------------------------------------------
// Kernel A: K/V projections only. Y(bf16) = Xb @ Wb^T + bias,
// blockIdx.z in {0,1} -> which in {1,2} = (Wk,bk,K) / (Wv,bv,V).
// 128x128 tile, BK=64 (32 KB LDS), global_load_lds x16, 16x16x32 bf16 MFMA,
// fp32 acc, XOR-swizzled LDS (slot s of row r holds global k-chunk s^(r&7)).
// ---------------------------------------------------------------------------
__global__ __launch_bounds__(256, 3) void kv_gemm_mfma(
    const unsigned short* __restrict__ Xb,
    const unsigned short* __restrict__ Wb,
    const float* __restrict__ bk, const float* __restrict__ bv,
    unsigned short* __restrict__ qkv)
{
    const int which = blockIdx.z + 1;                 // 1=K, 2=V
    const unsigned short* __restrict__ W = Wb + (size_t)which * (1024 * 1024);
    const float* __restrict__ bias = (which == 1) ? bk : bv;
    unsigned short* __restrict__ Y = qkv + (size_t)which * ((size_t)N_ROWS * E_DIM);

    __shared__ __align__(16) unsigned short Als[128 * 64];  // 16 KB
    __shared__ __align__(16) unsigned short Bls[128 * 64];  // 16 KB

    const int tid  = threadIdx.x;
    const int w    = tid >> 6;
    const int lane = tid & 63;
    const int m0 = blockIdx.x * 128;
    const int n0 = blockIdx.y * 128;
    const int wm = (w >> 1) * 64;
    const int wn = (w & 1) * 64;

    f32x4 acc[4][4];
    #pragma unroll
    for (int i = 0; i < 4; ++i)
        #pragma unroll
        for (int j = 0; j < 4; ++j)
            acc[i][j] = f32x4{0.f, 0.f, 0.f, 0.f};

    const int srow = lane >> 3;                       // 0..7
    const int skc  = ((lane & 7) ^ (lane >> 3)) * 8;  // swizzled global chunk
    const int quad = lane >> 4;
    const int fm   = lane & 15;
    const int sw8  = fm & 7;

    for (int k0 = 0; k0 < E_DIM; k0 += 64) {
        #pragma unroll
        for (int c = 0; c < 4; ++c) {
            const int r = w * 32 + c * 8;
            gl_lds16((const void*)(Xb + (size_t)(m0 + r + srow) * E_DIM + k0 + skc),
                     (void*)((char*)Als + r * 128 + lane * 16));
            gl_lds16((const void*)(W + (size_t)(n0 + r + srow) * E_DIM + k0 + skc),
                     (void*)((char*)Bls + r * 128 + lane * 16));
        }
        __syncthreads();

        #pragma unroll
        for (int kk = 0; kk < 2; ++kk) {
            const int slot = ((kk * 4 + quad) ^ sw8) * 8;
            bf16x8 af[4], bf[4];
            #pragma unroll
            for (int t = 0; t < 4; ++t) {
                af[t] = *(const bf16x8*)(Als + (wm + t * 16 + fm) * 64 + slot);
                bf[t] = *(const bf16x8*)(Bls + (wn + t * 16 + fm) * 64 + slot);
            }
            #pragma unroll
            for (int rt = 0; rt < 4; ++rt)
                #pragma unroll
                for (int ct = 0; ct < 4; ++ct)
                    acc[rt][ct] = __builtin_amdgcn_mfma_f32_16x16x32_bf16(
                        af[rt], bf[ct], acc[rt][ct], 0, 0, 0);
        }
        __syncthreads();
    }

    float bcol[4];
    #pragma unroll
    for (int ct = 0; ct < 4; ++ct) bcol[ct] = bias[n0 + wn + ct * 16 + fm];

    const int rbase = (lane >> 4) * 4;
    #pragma unroll
    for (int rt = 0; rt < 4; ++rt) {
        #pragma unroll
        for (int ct = 0; ct < 4; ++ct) {
            #pragma unroll
            for (int r = 0; r < 4; ++r) {
                const int row = m0 + wm + rt * 16 + rbase + r;
                const int col = n0 + wn + ct * 16 + fm;
                Y[(size_t)row * E_DIM + col] = f2b(acc[rt][ct][r] + bcol[ct]);
            }
        }
    }
}

// ---------------------------------------------------------------------------
// Kernel B: kT via MFMA. Block (i, c): 256-row chunk of attention block i.
//   Ppart[d][e] = sum_{r in chunk} V[r][d] * K[r][e]
// K,V staged transposed+swizzled in LDS; D[m=d][n=e] = sum_k A[m][k]B[n][k].
// ---------------------------------------------------------------------------
__global__ __launch_bounds__(256) void kT_mfma(
    const unsigned short* __restrict__ qkv, float* __restrict__ P)
{
    const size_t base = (size_t)blockIdx.x * (2048 * 64) + (size_t)blockIdx.y * (256 * 64);
    const unsigned short* __restrict__ Kb = qkv + KB_U + base;
    const unsigned short* __restrict__ Vb = qkv + VB_U + base;
    float* __restrict__ Pout = P + ((size_t)blockIdx.x * 8 + blockIdx.y) * 4096;

    __shared__ __align__(16) unsigned short Kt[64 * 64];  // [e][r] swizzled
    __shared__ __align__(16) unsigned short Vt[64 * 64];  // [d][r] swizzled

    const int tid  = threadIdx.x;
    const int w    = tid >> 6;
    const int lane = tid & 63;
    const int rl   = tid & 63;
    const int eo   = (tid >> 6) * 16;
    const int quad = lane >> 4;
    const int fm   = lane & 15;
    const int sw8  = fm & 7;

    f32x4 acc[4];
    #pragma unroll
    for (int nt = 0; nt < 4; ++nt) acc[nt] = f32x4{0.f, 0.f, 0.f, 0.f};

    for (int rb = 0; rb < 256; rb += 64) {
        union { uint4 u; unsigned short s[8]; } k0, k1, v0, v1;
        const size_t ga = (size_t)(rb + rl) * 64 + eo;
        k0.u = *(const uint4*)(Kb + ga);
        k1.u = *(const uint4*)(Kb + ga + 8);
        v0.u = *(const uint4*)(Vb + ga);
        v1.u = *(const uint4*)(Vb + ga + 8);
        __syncthreads();
        #pragma unroll
        for (int j = 0; j < 8; ++j) {
            Kt[sw_idx(eo + j, rl)]     = k0.s[j];
            Kt[sw_idx(eo + 8 + j, rl)] = k1.s[j];
            Vt[sw_idx(eo + j, rl)]     = v0.s[j];
            Vt[sw_idx(eo + 8 + j, rl)] = v1.s[j];
        }
        __syncthreads();
        #pragma unroll
        for (int kk = 0; kk < 2; ++kk) {
            const int slot = ((kk * 4 + quad) ^ sw8) << 3;
            const bf16x8 af = *(const bf16x8*)(Vt + (w * 16 + fm) * 64 + slot);
            #pragma unroll
            for (int nt = 0; nt < 4; ++nt) {
                const bf16x8 bf = *(const bf16x8*)(Kt + (nt * 16 + fm) * 64 + slot);
                acc[nt] = __builtin_amdgcn_mfma_f32_16x16x32_bf16(af, bf, acc[nt], 0, 0, 0);
            }
        }
    }

    const int rbase = (lane >> 4) * 4;
    #pragma unroll
    for (int nt = 0; nt < 4; ++nt)
        #pragma unroll
        for (int r = 0; r < 4; ++r)
            Pout[(size_t)(w * 16 + rbase + r) * 64 + nt * 16 + fm] = acc[nt][r];
}

// ---------------------------------------------------------------------------
// Kernel C (fused): per block (i = blockIdx.x, n0 = blockIdx.y*128):
//   prologue: T[d][e] = sum_c P[i][c][d][e] -> bf16 swizzled in Tls (8 KB)
//   stage 1 : Q-tile (128x128) = Xb @ Wq^T  (identical m97-style loop)
//   epilogue: Q+bias -> bf16 into LDS (overlaying dead A/B tiles), then
//             out rows = 0.125 * Q_head @ T via a K=64 MFMA stage.
// Out row fr = (m0 + qrow)*16 + (2*blockIdx.y + hl), cols = d (64 fp32).
// ---------------------------------------------------------------------------
__global__ __launch_bounds__(256, 2) void q_gemm_out(
    const unsigned short* __restrict__ Xb,
    const unsigned short* __restrict__ Wb,   // Wq slab at offset 0
    const float* __restrict__ bq,
    const float* __restrict__ P,
    float* __restrict__ out)
{
    __shared__ __align__(16) unsigned short S[20480];   // 40 KB
    unsigned short* Als = S;             // [128][64] swizzled (stage 1 A)
    unsigned short* Bls = S + 8192;      // [128][64] swizzled (stage 1 B)
    unsigned short* Tls = S + 16384;     // [64][64]  swizzled (B2[d][e] = sum P)

    const int tid  = threadIdx.x;
    const int w    = tid >> 6;
    const int lane = tid & 63;
    const int m0 = blockIdx.x * 128;     // attention block i = blockIdx.x
    const int n0 = blockIdx.y * 128;     // heads 2*by, 2*by+1
    const int wm = (w >> 1) * 64;
    const int wn = (w & 1) * 64;
    const int quad = lane >> 4;
    const int fm   = lane & 15;
    const int sw8  = fm & 7;
    const int srow = lane >> 3;
    const int skc  = ((lane & 7) ^ (lane >> 3)) * 8;

    // ---- prologue: reduce the 8 P-chunks of block i into Tls ----
    {
        const int d  = tid >> 2;                       // 0..63
        const int e0 = (tid & 3) << 4;                 // 0,16,32,48
        const float* p = P + (size_t)blockIdx.x * 32768 + (size_t)d * 64 + e0;
        f32x4 s0{0.f,0.f,0.f,0.f}, s1{0.f,0.f,0.f,0.f};
        f32x4 s2{0.f,0.f,0.f,0.f}, s3{0.f,0.f,0.f,0.f};
        #pragma unroll
        for (int c = 0; c < 8; ++c) {
            s0 += *(const f32x4*)(p + (size_t)c * 4096);
            s1 += *(const f32x4*)(p + (size_t)c * 4096 + 4);
            s2 += *(const f32x4*)(p + (size_t)c * 4096 + 8);
            s3 += *(const f32x4*)(p + (size_t)c * 4096 + 12);
        }
        const int c0 = e0 >> 3;                        // even chunk index
        *(uint4*)(Tls + d * 64 + ((c0 ^ (d & 7)) << 3))       = pack8(s0, s1);
        *(uint4*)(Tls + d * 64 + (((c0 + 1) ^ (d & 7)) << 3)) = pack8(s2, s3);
    }

    // ---- stage 1: Q-tile GEMM (identical structure to kv_gemm_mfma) ----
    f32x4 acc[4][4];
    #pragma unroll
    for (int i = 0; i < 4; ++i)
        #pragma unroll
        for (int j = 0; j < 4; ++j)
            acc[i][j] = f32x4{0.f, 0.f, 0.f, 0.f};

    for (int k0 = 0; k0 < E_DIM; k0 += 64) {
        #pragma unroll
        for (int c = 0; c < 4; ++c) {
            const int r = w * 32 + c * 8;
            gl_lds16((const void*)(Xb + (size_t)(m0 + r + srow) * E_DIM + k0 + skc),
                     (void*)((char*)Als + r * 128 + lane * 16));
            gl_lds16((const void*)(Wb + (size_t)(n0 + r + srow) * E_DIM + k0 + skc),
                     (void*)((char*)Bls + r * 128 + lane * 16));
        }
        __syncthreads();

        #pragma unroll
        for (int kk = 0; kk < 2; ++kk) {
            const int slot = ((kk * 4 + quad) ^ sw8) * 8;
            bf16x8 af[4], bf[4];
            #pragma unroll
            for (int t = 0; t < 4; ++t) {
                af[t] = *(const bf16x8*)(Als + (wm + t * 16 + fm) * 64 + slot);
                bf[t] = *(const bf16x8*)(Bls + (wn + t * 16 + fm) * 64 + slot);
            }
            #pragma unroll
            for (int rt = 0; rt < 4; ++rt)
                #pragma unroll
                for (int ct = 0; ct < 4; ++ct)
                    acc[rt][ct] = __builtin_amdgcn_mfma_f32_16x16x32_bf16(
                        af[rt], bf[ct], acc[rt][ct], 0, 0, 0);
        }
        __syncthreads();
    }

    // ---- epilogue: Q+bias -> bf16 into LDS (A/B tiles are dead now) ----
    float bcol[4];
    #pragma unroll
    for (int ct = 0; ct < 4; ++ct) bcol[ct] = bq[n0 + wn + ct * 16 + fm];

    const int rbase = (lane >> 4) * 4;
    #pragma unroll
    for (int rt = 0; rt < 4; ++rt) {
        #pragma unroll
        for (int ct = 0; ct < 4; ++ct) {
            const int cl = wn + ct * 16 + fm;          // 0..127
            const int hb = (cl >> 6) << 13;            // head tile base (shorts)
            const int e  = cl & 63;
            #pragma unroll
            for (int r = 0; r < 4; ++r) {
                const int row = wm + rt * 16 + rbase + r;   // 0..127 local
                S[hb + sw_idx(row, e)] = f2b(acc[rt][ct][r] + bcol[ct]);
            }
        }
    }
    __syncthreads();

    // ---- stage 2: out = 0.125 * Q_head @ T   (K = 64) ----
    const int hl = w & 1;                    // head-local index (0/1)
    const int rh = w >> 1;                   // row half (0/1) -> 64 rows
    const unsigned short* Qs = S + hl * 8192;

    f32x4 acc2[4][4];
    #pragma unroll
    for (int i = 0; i < 4; ++i)
        #pragma unroll
        for (int j = 0; j < 4; ++j)
            acc2[i][j] = f32x4{0.f, 0.f, 0.f, 0.f};

    #pragma unroll
    for (int kk = 0; kk < 2; ++kk) {
        const int slot = ((kk * 4 + quad) ^ sw8) << 3;
        bf16x8 a2[4], b2[4];
        #pragma unroll
        for (int t = 0; t < 4; ++t) {
            a2[t] = *(const bf16x8*)(Qs + (rh * 64 + t * 16 + fm) * 64 + slot);
            b2[t] = *(const bf16x8*)(Tls + (t * 16 + fm) * 64 + slot);
        }
        #pragma unroll
        for (int mt = 0; mt < 4; ++mt)
            #pragma unroll
            for (int nt = 0; nt < 4; ++nt)
                acc2[mt][nt] = __builtin_amdgcn_mfma_f32_16x16x32_bf16(
                    a2[mt], b2[nt], acc2[mt][nt], 0, 0, 0);
    }

    const int h = blockIdx.y * 2 + hl;       // global head 0..15
    #pragma unroll
    for (int mt = 0; mt < 4; ++mt) {
        #pragma unroll
        for (int nt = 0; nt < 4; ++nt) {
            #pragma unroll
            for (int r = 0; r < 4; ++r) {
                const int grow = m0 + rh * 64 + mt * 16 + rbase + r;  // X row
                const size_t fr = (size_t)grow * 16 + h;              // flat row
                out[fr * 64 + nt * 16 + fm] = 0.125f * acc2[mt][nt][r];
            }
        }
    }
}

extern "C" void kernel_launch(void* const* d_in, const int* in_sizes, int n_in,
                              void* d_out, int out_size, void* d_ws, size_t ws_size,
                              hipStream_t stream)
{
    const float* x  = (const float*)d_in[0];
    const float* Wq = (const float*)d_in[1];
    const float* bq = (const float*)d_in[2];
    const float* Wk = (const float*)d_in[3];
    const float* bk = (const float*)d_in[4];
    const float* Wv = (const float*)d_in[5];
    const float* bv = (const float*)d_in[6];
    float* wsf = (float*)d_ws;
    unsigned short* wsu = (unsigned short*)d_ws;
    float* out = (float*)d_out;

    dim3 gCvt(512, 7);
    cvt_bf16<<<gCvt, 256, 0, stream>>>(x, Wq, Wk, Wv, wsu + XB_U);

    dim3 gKV(N_ROWS / 128, E_DIM / 128, 2);   // 32 x 8 x 2 (K and V only)
    kv_gemm_mfma<<<gKV, 256, 0, stream>>>(wsu + XB_U, wsu + WB_U,
                                          bk, bv, wsu);

    dim3 gB(32, 8);
    kT_mfma<<<gB, 256, 0, stream>>>(wsu, wsf + P_F);

    dim3 gQ(32, 8);
    q_gemm_out<<<gQ, 256, 0, stream>>>(wsu + XB_U, wsu + WB_U,
                                       bq, wsf + P_F, out);
}